// Round 11
// baseline (700.512 us; speedup 1.0000x reference)
//
#include <hip/hip_runtime.h>

#define BATCH 8
#define T 4096
#define NCH 256
#define NCTX 80
#define NLAYERS 8

typedef unsigned short u16;
typedef __attribute__((ext_vector_type(8))) short short8;
typedef __attribute__((ext_vector_type(4))) short short4v;
typedef __attribute__((ext_vector_type(4))) float float4v;

__device__ __forceinline__ float b2f(u16 u) {
    unsigned v = ((unsigned)u) << 16;
    float f;
    __builtin_memcpy(&f, &v, 4);
    return f;
}
__device__ __forceinline__ u16 f2b(float f) {
    unsigned v;
    __builtin_memcpy(&v, &f, 4);
    unsigned r = v + 0x7FFFu + ((v >> 16) & 1u);
    return (u16)(r >> 16);
}

typedef const __attribute__((address_space(1))) unsigned int* gp1;
typedef __attribute__((address_space(3))) unsigned int* lp3;
__device__ __forceinline__ void gl_lds16(const u16* g, u16* l) {
    __builtin_amdgcn_global_load_lds((gp1)g, (lp3)l, 16, 0, 0);
}

// full-drain barrier (R8-verified correct). With 2 co-resident blocks/CU the
// drain stall of one block is covered by the other block's waves (m114).
__device__ __forceinline__ void wbar() { asm volatile("s_waitcnt vmcnt(0) lgkmcnt(0)\n\ts_barrier" ::: "memory"); }

template <bool F32>
__device__ __forceinline__ float LD(const void* p, size_t i) {
    if constexpr (F32) return ((const float*)p)[i];
    else return b2f(((const u16*)p)[i]);
}

// ---------------- dtype probe ----------------
__global__ void probe_kernel(const u16* __restrict__ fc, int* __restrict__ flag) {
    __shared__ int cnt;
    if (threadIdx.x == 0) cnt = 0;
    __syncthreads();
    int local = 0;
#pragma unroll
    for (int j = 0; j < 16; j++) {
        u16 u = fc[2 * (threadIdx.x * 16 + j)];
        int e = (u >> 7) & 0xFF;
        if (e >= 0x50 && e <= 0x85) local++;
    }
    atomicAdd(&cnt, local);
    __syncthreads();
    if (threadIdx.x == 0) *flag = (cnt >= 2048) ? 1 : 0;  // 1 = bf16 inputs
}

// ---------------- generic convert to bf16 (runtime dtype branch; one launch) ----------------
__global__ void cvt_kernel(const void* __restrict__ src, u16* __restrict__ dst, int n,
                           const int* __restrict__ flag) {
    int i = blockIdx.x * 256 + threadIdx.x;
    if (i >= n) return;
    if (*flag) dst[i] = f2b(LD<false>(src, i));
    else       dst[i] = f2b(LD<true>(src, i));
}

// ---------------- build Wc [8][512][864] ----------------
template <bool F32>
__device__ __forceinline__ void prep_wc_body(const void* __restrict__ in_w,
                                             const void* __restrict__ in_b,
                                             const void* __restrict__ cond_w,
                                             const void* __restrict__ cond_b,
                                             u16* __restrict__ Wc) {
    int row = blockIdx.x;  // 0..4095 = l*512+o
    for (int it = 0; it < 4; it++) {
        int col = it * 256 + threadIdx.x;
        if (col >= 864) break;
        float v;
        if (col < 256)       v = LD<F32>(in_w, ((size_t)row * 256 + col) * 3);
        else if (col < 512)  v = LD<F32>(in_w, ((size_t)row * 256 + (col - 256)) * 3 + 1);
        else if (col < 768)  v = LD<F32>(in_w, ((size_t)row * 256 + (col - 512)) * 3 + 2);
        else if (col < 848)  v = LD<F32>(cond_w, (size_t)row * 80 + (col - 768));
        else if (col == 848) v = LD<F32>(in_b, row) + LD<F32>(cond_b, row);
        else                 v = 0.f;
        Wc[(size_t)row * 864 + col] = f2b(v);
    }
}
__global__ void prep_wc(const void* __restrict__ in_w, const void* __restrict__ in_b,
                        const void* __restrict__ cond_w, const void* __restrict__ cond_b,
                        u16* __restrict__ Wc, const int* __restrict__ flag) {
    if (*flag) prep_wc_body<false>(in_w, in_b, cond_w, cond_b, Wc);
    else       prep_wc_body<true>(in_w, in_b, cond_w, cond_b, Wc);
}

// ---------------- transpose context -> ctx_t [B][T][96] ----------------
template <bool F32>
__device__ __forceinline__ void prep_ctx_body(const void* __restrict__ ctx,
                                              u16* __restrict__ ctxt, float (*sm)[65]) {
    const int tid = threadIdx.x;
    const int b = blockIdx.y, t0 = blockIdx.x * 64;
    for (int it = 0; it < 20; it++) {
        int e = it * 256 + tid;
        int j = e >> 6, tt = e & 63;
        sm[j][tt] = LD<F32>(ctx, ((size_t)b * 80 + j) * T + t0 + tt);
    }
    __syncthreads();
    for (int it = 0; it < 24; it++) {
        int e = it * 256 + tid;
        int r = e / 96, c = e - r * 96;
        float v = (c < 80) ? sm[c][r] : (c == 80 ? 1.f : 0.f);
        ctxt[((size_t)b * T + t0 + r) * 96 + c] = f2b(v);
    }
}
__global__ void prep_ctx(const void* __restrict__ ctx, u16* __restrict__ ctxt,
                         const int* __restrict__ flag) {
    __shared__ float sm[80][65];
    if (*flag) prep_ctx_body<false>(ctx, ctxt, sm);
    else       prep_ctx_body<true>(ctx, ctxt, sm);
}

// ---------------- start conv (4 -> 256, 1x1) -> x_t [B][T][256] ----------------
template <bool F32>
__device__ __forceinline__ void start_body(const void* __restrict__ fc,
                                           const void* __restrict__ w,
                                           const void* __restrict__ bias,
                                           u16* __restrict__ xt, float (*fsm)[64],
                                           float* wsm, float* bsm) {
    const int tid = threadIdx.x;
    const int b = blockIdx.y, t0 = blockIdx.x * 64;
    fsm[tid >> 6][tid & 63] = LD<F32>(fc, ((size_t)b * 8 + (tid >> 6)) * T + t0 + (tid & 63));
    for (int it = 0; it < 4; it++) wsm[it * 256 + tid] = LD<F32>(w, it * 256 + tid);
    bsm[tid] = LD<F32>(bias, tid);
    __syncthreads();
    for (int r = 0; r < 64; r++) {
        int c = tid;
        float a = bsm[c];
#pragma unroll
        for (int k = 0; k < 4; k++) a += wsm[c * 4 + k] * fsm[k][r];
        xt[((size_t)b * T + t0 + r) * 256 + c] = f2b(a);
    }
}
__global__ void start_kernel(const void* __restrict__ fc, const void* __restrict__ w,
                             const void* __restrict__ bias, u16* __restrict__ xt,
                             const int* __restrict__ flag) {
    __shared__ float fsm[4][64];
    __shared__ float wsm[1024];
    __shared__ float bsm[256];
    if (*flag) start_body<false>(fc, w, bias, xt, fsm, wsm, bsm);
    else       start_body<true>(fc, w, bias, xt, fsm, wsm, bsm);
}

// ================= layer conv kernel: dilated conv+cond GEMM + gate -> acts =================
// R11 OCCUPANCY EXPERIMENT: grid (T/64=64, B=8)=512 blocks, 512 threads, 2 BLOCKS/CU
// (16 waves/CU, launch_bounds(512,4)). Block tile 64t x 512 GEMM-cols; 8 waves =
// 2 iw (32-row halves) x 4 jc. Same paired-permutation B as R4 (jj<4 tanh rows of Wc,
// jj>=4 sigm rows of SAME channels -> in-wave gate); same swizzles, same staging maps.
// A/B DOUBLE-buffered (fits 2 blocks: 72KB LDS each) -> drain-per-step (R8-verified
// schedule); the drain stall is covered by the co-resident block's waves.
// LDS u16: A dbl 2x2048 @[0,4096), B dbl 2x16384 @[4096,36864). 73,728 B.
__global__ __launch_bounds__(512, 4) void layer_conv(
    const u16* __restrict__ x, const u16* __restrict__ Wc, const u16* __restrict__ ctxt,
    u16* __restrict__ acts, int layer, int dil) {
    __shared__ u16 lds[36864];
    const int tid = threadIdx.x;
    const int w = tid >> 6, lane = tid & 63;
    const int l15 = lane & 15, quad = lane >> 4;
    const int iw = w >> 2, jc = w & 3;   // wave tile: t-rows 32*iw, out-col pair 64*jc
    const int b = blockIdx.y, t0 = blockIdx.x * 64;
    const int lrow = lane >> 2;                                   // 0..15
    const int fw = (lrow ^ (lrow >> 2)) & 3;                      // writer-side f(row)
    const int lsw = ((lane & 3) ^ fw) * 8;                        // swizzled src chunk (u16)
    const int fr = (l15 ^ (l15 >> 2)) & 3;                        // reader-side f(row)
    const int rq = (quad ^ fr) * 8;                               // swizzled reader chunk (u16)
    const int brb = 64 * (w >> 1) + 256 * (w & 1);                // B-stage row base (paired perm)

    const u16* xb = x + (size_t)b * T * 256;
    const u16* cb = ctxt + (size_t)b * T * 96;
    const u16* Wl = Wc + (size_t)layer * 512 * 864;

    float4v acc[2][8];  // [m][jj]: jj<4 tanh half, jj>=4 sigm half (same cols)
#pragma unroll
    for (int m = 0; m < 2; m++)
#pragma unroll
        for (int jj = 0; jj < 8; jj++) acc[m][jj] = (float4v){0.f, 0.f, 0.f, 0.f};

    // stage A K-step s: 64 rows x 32 u16 (4KB); waves 0-3 stage rows 16w..16w+15.
    auto stageA = [&](int s, int abuf) {
        if (w >= 4) return;
        u16* dst = &lds[abuf * 2048 + w * 512];
        if (s < 24) {
            int seg = s >> 3, cs = s & 7;
            int tb = t0 + 16 * w + (seg - 1) * dil;
            if (tb >= 0 && tb + 16 <= T) {
                gl_lds16(xb + (size_t)(tb + lrow) * 256 + cs * 32 + lsw, dst);
            } else {  // boundary tile: manual masked path (rare)
                int t = tb + lrow;
                short8 av = (short8){0, 0, 0, 0, 0, 0, 0, 0};
                if (t >= 0 && t < T)
                    av = *(const short8*)(xb + (size_t)t * 256 + cs * 32 + lsw);
                *(short4v*)&dst[lane * 8] = __builtin_shufflevector(av, av, 0, 1, 2, 3);
                *(short4v*)&dst[lane * 8 + 4] = __builtin_shufflevector(av, av, 4, 5, 6, 7);
            }
        } else {
            gl_lds16(cb + (size_t)(t0 + 16 * w + lrow) * 96 + (s - 24) * 32 + lsw, dst);
        }
    };
    // stage B K-step s: 512 rows x 32 u16 (32KB); wave w stages 64 rows from brb.
    auto stageB = [&](int s, int bbuf) {
        const u16* src = Wl + (size_t)(brb + lrow) * 864 + s * 32 + lsw;
        u16* dst = &lds[4096 + bbuf * 16384 + w * 2048];
        gl_lds16(src, dst);
        gl_lds16(src + (size_t)16 * 864, dst + 512);
        gl_lds16(src + (size_t)32 * 864, dst + 1024);
        gl_lds16(src + (size_t)48 * 864, dst + 1536);
    };
    auto compute = [&](int s) {
        const u16* bA = &lds[(s & 1) * 2048];
        const u16* bB = &lds[4096 + (s & 1) * 16384];
        short8 af0 = *(const short8*)&bA[(32 * iw + l15) * 32 + rq];
        short8 af1 = *(const short8*)&bA[(32 * iw + 16 + l15) * 32 + rq];
        __builtin_amdgcn_s_setprio(1);
#pragma unroll
        for (int jj = 0; jj < 8; jj++) {
            short8 bf = *(const short8*)&bB[(128 * jc + 16 * jj + l15) * 32 + rq];
            acc[0][jj] = __builtin_amdgcn_mfma_f32_16x16x32_bf16(af0, bf, acc[0][jj], 0, 0, 0);
            acc[1][jj] = __builtin_amdgcn_mfma_f32_16x16x32_bf16(af1, bf, acc[1][jj], 0, 0, 0);
        }
        __builtin_amdgcn_s_setprio(0);
    };

    stageA(0, 0);
    stageB(0, 0);
    wbar();
#pragma unroll 1
    for (int s = 0; s < 27; s++) {
        if (s + 1 < 27) {
            stageA(s + 1, (s + 1) & 1);  // write buf (s+1)&1; compute reads s&1: disjoint
            stageB(s + 1, (s + 1) & 1);
        }
        compute(s);
        if (s + 1 < 27) wbar();          // drain next-step stages (covered by co-block)
    }

    // gate in-wave: acc[m][jj] = tanh input, acc[m][jj+4] = sigm input, same col.
    u16* ab = acts + (size_t)b * T * 256;
#pragma unroll
    for (int m = 0; m < 2; m++)
#pragma unroll
        for (int jj = 0; jj < 4; jj++) {
            int o = 64 * jc + 16 * jj + l15;
#pragma unroll
            for (int r = 0; r < 4; r++) {
                int t = t0 + 32 * iw + 16 * m + quad * 4 + r;
                float at = acc[m][jj][r], as = acc[m][jj + 4][r];
                float e2 = __expf(2.f * at);
                float th = 1.f - 2.f / (e2 + 1.f);
                float sg = 1.f / (1.f + __expf(-as));
                ab[(size_t)t * 256 + o] = f2b(th * sg);
            }
        }
}

// ================= layer rs kernel: 1x1 conv (K=256) + residual/skip update =================
// Same 2-blocks/CU geometry + paired permutation (jj<4 residual, jj>=4 skip, same cols).
__global__ __launch_bounds__(512, 4) void layer_rs(
    const u16* __restrict__ acts, u16* __restrict__ x, const u16* __restrict__ Wrs,
    const u16* __restrict__ rsb, u16* __restrict__ oacc, int layer, int first, int last) {
    __shared__ u16 lds[36864];
    const int tid = threadIdx.x;
    const int w = tid >> 6, lane = tid & 63;
    const int l15 = lane & 15, quad = lane >> 4;
    const int iw = w >> 2, jc = w & 3;
    const int b = blockIdx.y, t0 = blockIdx.x * 64;
    const int lrow = lane >> 2;
    const int fw = (lrow ^ (lrow >> 2)) & 3;
    const int lsw = ((lane & 3) ^ fw) * 8;
    const int fr = (l15 ^ (l15 >> 2)) & 3;
    const int rq = (quad ^ fr) * 8;
    const int brb = 64 * (w >> 1) + 256 * (w & 1);

    const u16* ab = acts + (size_t)b * T * 256;
    const u16* Wr = Wrs + (size_t)layer * 512 * 256;

    float4v acc[2][8];
#pragma unroll
    for (int m = 0; m < 2; m++)
#pragma unroll
        for (int jj = 0; jj < 8; jj++) acc[m][jj] = (float4v){0.f, 0.f, 0.f, 0.f};

    auto stageA = [&](int s, int abuf) {
        if (w >= 4) return;
        gl_lds16(ab + (size_t)(t0 + 16 * w + lrow) * 256 + s * 32 + lsw,
                 &lds[abuf * 2048 + w * 512]);
    };
    auto stageB = [&](int s, int bbuf) {
        const u16* src = Wr + (size_t)(brb + lrow) * 256 + s * 32 + lsw;
        u16* dst = &lds[4096 + bbuf * 16384 + w * 2048];
        gl_lds16(src, dst);
        gl_lds16(src + (size_t)16 * 256, dst + 512);
        gl_lds16(src + (size_t)32 * 256, dst + 1024);
        gl_lds16(src + (size_t)48 * 256, dst + 1536);
    };
    auto compute = [&](int s) {
        const u16* bA = &lds[(s & 1) * 2048];
        const u16* bB = &lds[4096 + (s & 1) * 16384];
        short8 af0 = *(const short8*)&bA[(32 * iw + l15) * 32 + rq];
        short8 af1 = *(const short8*)&bA[(32 * iw + 16 + l15) * 32 + rq];
        __builtin_amdgcn_s_setprio(1);
#pragma unroll
        for (int jj = 0; jj < 8; jj++) {
            short8 bf = *(const short8*)&bB[(128 * jc + 16 * jj + l15) * 32 + rq];
            acc[0][jj] = __builtin_amdgcn_mfma_f32_16x16x32_bf16(af0, bf, acc[0][jj], 0, 0, 0);
            acc[1][jj] = __builtin_amdgcn_mfma_f32_16x16x32_bf16(af1, bf, acc[1][jj], 0, 0, 0);
        }
        __builtin_amdgcn_s_setprio(0);
    };

    stageA(0, 0);
    stageB(0, 0);
    wbar();
#pragma unroll 1
    for (int s = 0; s < 8; s++) {
        if (s + 1 < 8) {
            stageA(s + 1, (s + 1) & 1);
            stageB(s + 1, (s + 1) & 1);
        }
        compute(s);
        if (s + 1 < 8) wbar();
    }

    u16* xv = x + (size_t)b * T * 256;
    u16* oo = oacc + (size_t)b * T * 256;
#pragma unroll
    for (int m = 0; m < 2; m++)
#pragma unroll
        for (int jj = 0; jj < 8; jj++) {
            int o = 64 * jc + 16 * (jj & 3) + l15;
            if (jj < 4) {  // residual half (Wrs rows 0..255)
                float b0 = b2f(rsb[layer * 512 + o]);
#pragma unroll
                for (int r = 0; r < 4; r++) {
                    int t = t0 + 32 * iw + 16 * m + quad * 4 + r;
                    size_t idx = (size_t)t * 256 + o;
                    float v0 = acc[m][jj][r] + b0;
                    if (last) oo[idx] = f2b(b2f(oo[idx]) + v0);   // last: rs[:256] -> skip
                    else      xv[idx] = f2b(b2f(xv[idx]) + v0);   // residual (in place)
                }
            } else if (!last) {  // skip half (Wrs rows 256..511)
                float b1 = b2f(rsb[layer * 512 + 256 + o]);
#pragma unroll
                for (int r = 0; r < 4; r++) {
                    int t = t0 + 32 * iw + 16 * m + quad * 4 + r;
                    size_t idx = (size_t)t * 256 + o;
                    float v1 = acc[m][jj][r] + b1;
                    oo[idx] = first ? f2b(v1) : f2b(b2f(oo[idx]) + v1);
                }
            }
        }
}

// ---------------- end conv (256 -> 8) + affine + output assembly ----------------
template <bool F32>
__device__ __forceinline__ void end_body(const u16* __restrict__ oacc,
                                         const void* __restrict__ w_end,
                                         const void* __restrict__ b_end,
                                         const void* __restrict__ fc, void* __restrict__ out,
                                         float* wsm, float* bsm) {
    const int tid = threadIdx.x;
    for (int it = 0; it < 8; it++) wsm[it * 256 + tid] = LD<F32>(w_end, it * 256 + tid);
    if (tid < 8) bsm[tid] = LD<F32>(b_end, tid);
    __syncthreads();
    int gid = blockIdx.x * 256 + tid;  // 0..32767
    int b = gid >> 12, t = gid & 4095;
    float o8[8];
#pragma unroll
    for (int o = 0; o < 8; o++) o8[o] = bsm[o];
    const u16* orow = oacc + (size_t)(b * T + t) * 256;
    for (int c8 = 0; c8 < 32; c8++) {
        short8 v8 = *(const short8*)(orow + c8 * 8);
#pragma unroll
        for (int k = 0; k < 8; k++) {
            float v = b2f((u16)v8[k]);
            int c = c8 * 8 + k;
#pragma unroll
            for (int o = 0; o < 8; o++) o8[o] += wsm[o * 256 + c] * v;
        }
    }
    size_t ob8 = (size_t)b * 8 * T;
#pragma unroll
    for (int j = 0; j < 4; j++) {
        float f1v = LD<F32>(fc, ob8 + (size_t)(4 + j) * T + t);
        float ls = o8[4 + j];
        float val = __expf(ls) * f1v + o8[j];
        if constexpr (F32) {
            float* o = (float*)out;
            o[ob8 + (size_t)j * T + t] = ((const float*)fc)[ob8 + (size_t)j * T + t];
            o[ob8 + (size_t)(4 + j) * T + t] = val;
            o[(size_t)BATCH * 8 * T + ((size_t)b * 4 + j) * T + t] = ls;
        } else {
            u16* o = (u16*)out;
            o[ob8 + (size_t)j * T + t] = ((const u16*)fc)[ob8 + (size_t)j * T + t];
            o[ob8 + (size_t)(4 + j) * T + t] = f2b(val);
            o[(size_t)BATCH * 8 * T + ((size_t)b * 4 + j) * T + t] = f2b(ls);
        }
    }
}
__global__ void end_kernel(const u16* __restrict__ oacc, const void* __restrict__ w_end,
                           const void* __restrict__ b_end, const void* __restrict__ fc,
                           void* __restrict__ out, const int* __restrict__ flag) {
    __shared__ float wsm[2048];
    __shared__ float bsm[8];
    if (*flag) end_body<false>(oacc, w_end, b_end, fc, out, wsm, bsm);
    else       end_body<true>(oacc, w_end, b_end, fc, out, wsm, bsm);
}

extern "C" void kernel_launch(void* const* d_in, const int* in_sizes, int n_in,
                              void* d_out, int out_size, void* d_ws, size_t ws_size,
                              hipStream_t stream) {
    const void* forecast = d_in[0];
    const void* context  = d_in[1];
    const void* start_w  = d_in[2];
    const void* start_b  = d_in[3];
    const void* cond_w   = d_in[4];
    const void* cond_b   = d_in[5];
    const void* in_w     = d_in[6];
    const void* in_b     = d_in[7];
    const void* rs_w     = d_in[8];
    const void* rs_b     = d_in[9];
    const void* end_w    = d_in[10];
    const void* end_b    = d_in[11];

    char* W = (char*)d_ws;
    int* flag = (int*)(W + 0);
    u16* xA   = (u16*)(W + 256);                  // 16,777,216
    u16* oacc = (u16*)(W + 256 + 16777216);       // 16,777,216
    u16* acts = (u16*)(W + 256 + 33554432);       // 16,777,216
    u16* ctxt = (u16*)(W + 256 + 50331648);       //  6,291,456
    u16* Wc   = (u16*)(W + 256 + 56623104);       //  7,077,888
    u16* Wrs  = (u16*)(W + 256 + 63700992);       //  2,097,152
    u16* rsb  = (u16*)(W + 256 + 65798144);       //      8,192  -> total ~62.8 MiB

    probe_kernel<<<1, 256, 0, stream>>>((const u16*)forecast, flag);

    // single-pass prep (runtime dtype branch inside each kernel)
    cvt_kernel<<<4096, 256, 0, stream>>>(rs_w, Wrs, 8 * 512 * 256, flag);
    cvt_kernel<<<16, 256, 0, stream>>>(rs_b, rsb, 4096, flag);
    prep_wc<<<4096, 256, 0, stream>>>(in_w, in_b, cond_w, cond_b, Wc, flag);
    prep_ctx<<<dim3(64, BATCH), 256, 0, stream>>>(context, ctxt, flag);
    start_kernel<<<dim3(64, BATCH), 256, 0, stream>>>(forecast, start_w, start_b, xA, flag);

    const int dil[NLAYERS] = {1, 2, 4, 8, 16, 32, 64, 128};
    for (int l = 0; l < NLAYERS; l++) {
        layer_conv<<<dim3(64, BATCH), 512, 0, stream>>>(xA, Wc, ctxt, acts, l, dil[l]);
        layer_rs<<<dim3(64, BATCH), 512, 0, stream>>>(acts, xA, Wrs, rsb, oacc, l,
                                                      l == 0, l == NLAYERS - 1);
    }

    end_kernel<<<128, 256, 0, stream>>>(oacc, end_w, end_b, forecast, d_out, flag);
}

// Round 12
// 671.684 us; speedup vs baseline: 1.0429x; 1.0429x over previous
//
#include <hip/hip_runtime.h>

#define BATCH 8
#define T 4096
#define NCH 256
#define NCTX 80
#define NLAYERS 8

typedef unsigned short u16;
typedef __attribute__((ext_vector_type(8))) short short8;
typedef __attribute__((ext_vector_type(4))) short short4v;
typedef __attribute__((ext_vector_type(4))) float float4v;

__device__ __forceinline__ float b2f(u16 u) {
    unsigned v = ((unsigned)u) << 16;
    float f;
    __builtin_memcpy(&f, &v, 4);
    return f;
}
__device__ __forceinline__ u16 f2b(float f) {
    unsigned v;
    __builtin_memcpy(&v, &f, 4);
    unsigned r = v + 0x7FFFu + ((v >> 16) & 1u);
    return (u16)(r >> 16);
}

typedef const __attribute__((address_space(1))) unsigned int* gp1;
typedef __attribute__((address_space(3))) unsigned int* lp3;
__device__ __forceinline__ void gl_lds16(const u16* g, u16* l) {
    __builtin_amdgcn_global_load_lds((gp1)g, (lp3)l, 16, 0, 0);
}

// counted-vmcnt barriers (T3+T4, verified R4/R10): allow the N newest loads to
// stay in flight across the barrier; oldest-first retirement guarantees the
// buffers needed next step have landed. Never drain to 0 in steady state.
// lgkmcnt(0) covers the rare boundary ds_write path (free in steady state).
__device__ __forceinline__ void wb0() { asm volatile("s_waitcnt vmcnt(0) lgkmcnt(0)\n\ts_barrier" ::: "memory"); }
__device__ __forceinline__ void wb4() { asm volatile("s_waitcnt vmcnt(4) lgkmcnt(0)\n\ts_barrier" ::: "memory"); }
__device__ __forceinline__ void wb5() { asm volatile("s_waitcnt vmcnt(5) lgkmcnt(0)\n\ts_barrier" ::: "memory"); }

template <bool F32>
__device__ __forceinline__ float LD(const void* p, size_t i) {
    if constexpr (F32) return ((const float*)p)[i];
    else return b2f(((const u16*)p)[i]);
}

// ---------------- dtype probe ----------------
__global__ void probe_kernel(const u16* __restrict__ fc, int* __restrict__ flag) {
    __shared__ int cnt;
    if (threadIdx.x == 0) cnt = 0;
    __syncthreads();
    int local = 0;
#pragma unroll
    for (int j = 0; j < 16; j++) {
        u16 u = fc[2 * (threadIdx.x * 16 + j)];
        int e = (u >> 7) & 0xFF;
        if (e >= 0x50 && e <= 0x85) local++;
    }
    atomicAdd(&cnt, local);
    __syncthreads();
    if (threadIdx.x == 0) *flag = (cnt >= 2048) ? 1 : 0;  // 1 = bf16 inputs
}

// ---------------- generic convert to bf16 (runtime dtype branch; one launch) ----------------
__global__ void cvt_kernel(const void* __restrict__ src, u16* __restrict__ dst, int n,
                           const int* __restrict__ flag) {
    int i = blockIdx.x * 256 + threadIdx.x;
    if (i >= n) return;
    if (*flag) dst[i] = f2b(LD<false>(src, i));
    else       dst[i] = f2b(LD<true>(src, i));
}

// ---------------- build Wc [8][512][864] ----------------
template <bool F32>
__device__ __forceinline__ void prep_wc_body(const void* __restrict__ in_w,
                                             const void* __restrict__ in_b,
                                             const void* __restrict__ cond_w,
                                             const void* __restrict__ cond_b,
                                             u16* __restrict__ Wc) {
    int row = blockIdx.x;  // 0..4095 = l*512+o
    for (int it = 0; it < 4; it++) {
        int col = it * 256 + threadIdx.x;
        if (col >= 864) break;
        float v;
        if (col < 256)       v = LD<F32>(in_w, ((size_t)row * 256 + col) * 3);
        else if (col < 512)  v = LD<F32>(in_w, ((size_t)row * 256 + (col - 256)) * 3 + 1);
        else if (col < 768)  v = LD<F32>(in_w, ((size_t)row * 256 + (col - 512)) * 3 + 2);
        else if (col < 848)  v = LD<F32>(cond_w, (size_t)row * 80 + (col - 768));
        else if (col == 848) v = LD<F32>(in_b, row) + LD<F32>(cond_b, row);
        else                 v = 0.f;
        Wc[(size_t)row * 864 + col] = f2b(v);
    }
}
__global__ void prep_wc(const void* __restrict__ in_w, const void* __restrict__ in_b,
                        const void* __restrict__ cond_w, const void* __restrict__ cond_b,
                        u16* __restrict__ Wc, const int* __restrict__ flag) {
    if (*flag) prep_wc_body<false>(in_w, in_b, cond_w, cond_b, Wc);
    else       prep_wc_body<true>(in_w, in_b, cond_w, cond_b, Wc);
}

// ---------------- transpose context -> ctx_t [B][T][96] ----------------
template <bool F32>
__device__ __forceinline__ void prep_ctx_body(const void* __restrict__ ctx,
                                              u16* __restrict__ ctxt, float (*sm)[65]) {
    const int tid = threadIdx.x;
    const int b = blockIdx.y, t0 = blockIdx.x * 64;
    for (int it = 0; it < 20; it++) {
        int e = it * 256 + tid;
        int j = e >> 6, tt = e & 63;
        sm[j][tt] = LD<F32>(ctx, ((size_t)b * 80 + j) * T + t0 + tt);
    }
    __syncthreads();
    for (int it = 0; it < 24; it++) {
        int e = it * 256 + tid;
        int r = e / 96, c = e - r * 96;
        float v = (c < 80) ? sm[c][r] : (c == 80 ? 1.f : 0.f);
        ctxt[((size_t)b * T + t0 + r) * 96 + c] = f2b(v);
    }
}
__global__ void prep_ctx(const void* __restrict__ ctx, u16* __restrict__ ctxt,
                         const int* __restrict__ flag) {
    __shared__ float sm[80][65];
    if (*flag) prep_ctx_body<false>(ctx, ctxt, sm);
    else       prep_ctx_body<true>(ctx, ctxt, sm);
}

// ---------------- start conv (4 -> 256, 1x1) -> x_t [B][T][256] ----------------
template <bool F32>
__device__ __forceinline__ void start_body(const void* __restrict__ fc,
                                           const void* __restrict__ w,
                                           const void* __restrict__ bias,
                                           u16* __restrict__ xt, float (*fsm)[64],
                                           float* wsm, float* bsm) {
    const int tid = threadIdx.x;
    const int b = blockIdx.y, t0 = blockIdx.x * 64;
    fsm[tid >> 6][tid & 63] = LD<F32>(fc, ((size_t)b * 8 + (tid >> 6)) * T + t0 + (tid & 63));
    for (int it = 0; it < 4; it++) wsm[it * 256 + tid] = LD<F32>(w, it * 256 + tid);
    bsm[tid] = LD<F32>(bias, tid);
    __syncthreads();
    for (int r = 0; r < 64; r++) {
        int c = tid;
        float a = bsm[c];
#pragma unroll
        for (int k = 0; k < 4; k++) a += wsm[c * 4 + k] * fsm[k][r];
        xt[((size_t)b * T + t0 + r) * 256 + c] = f2b(a);
    }
}
__global__ void start_kernel(const void* __restrict__ fc, const void* __restrict__ w,
                             const void* __restrict__ bias, u16* __restrict__ xt,
                             const int* __restrict__ flag) {
    __shared__ float fsm[4][64];
    __shared__ float wsm[1024];
    __shared__ float bsm[256];
    if (*flag) start_body<false>(fc, w, bias, xt, fsm, wsm, bsm);
    else       start_body<true>(fc, w, bias, xt, fsm, wsm, bsm);
}

// ================= layer conv kernel (R10-verified structure + T1 XCD swizzle) =================
// grid (T/128=32, B=8), 512 threads (8 waves = 2 iw x 4 jc). Wave tile 64t x 128
// GEMM-cols; COLUMN-PAIRED B permutation: jj<4 = tanh rows of Wc (0..255), jj>=4 =
// sigm rows (256..511) of the SAME channels -> in-wave gate, no exchange, no spill.
// One chunk per K-step (27): A(s+2)[1 DMA] + B(s+2)[4 DMA]; counted vmcnt(4+a).
// T1 XCD swizzle (bijective, 256%8==0): lin=bx+32*by; b=lin&7, tile=lin>>3 -> each
// XCD's 32 blocks share one x[b] panel (2MB) + Wc slice (0.9MB) + ctxt slice: L2-fits.
// LDS u16: A tri 3x4096 @[0,12288), B tri 3x16384 @[12288,61440). 122,880 B.
__global__ __launch_bounds__(512, 1) void layer_conv(
    const u16* __restrict__ x, const u16* __restrict__ Wc, const u16* __restrict__ ctxt,
    u16* __restrict__ acts, int layer, int dil) {
    __shared__ u16 lds[61440];
    const int tid = threadIdx.x;
    const int w = tid >> 6, lane = tid & 63;
    const int l15 = lane & 15, quad = lane >> 4;
    const int iw = w >> 2, jc = w & 3;   // wave tile: t-rows 64*iw, out-col pair 64*jc
    const int lin = blockIdx.x + 32 * blockIdx.y;                 // 0..255
    const int b = lin & 7, t0 = (lin >> 3) * 128;                 // T1 XCD swizzle
    const int lrow = lane >> 2;                                   // 0..15
    const int fw = (lrow ^ (lrow >> 2)) & 3;                      // writer-side f(row)
    const int lsw = ((lane & 3) ^ fw) * 8;                        // swizzled src chunk (u16)
    const int fr = (l15 ^ (l15 >> 2)) & 3;                        // reader-side f(row)
    const int rq = (quad ^ fr) * 8;                               // swizzled reader chunk (u16)
    const int brb = 64 * (w >> 1) + 256 * (w & 1);                // B-stage row base (paired perm)

    const u16* xb = x + (size_t)b * T * 256;
    const u16* cb = ctxt + (size_t)b * T * 96;
    const u16* Wl = Wc + (size_t)layer * 512 * 864;

    float4v acc[4][8];  // [m][jj]: jj<4 tanh half, jj>=4 sigm half (same cols)
#pragma unroll
    for (int m = 0; m < 4; m++)
#pragma unroll
        for (int jj = 0; jj < 8; jj++) acc[m][jj] = (float4v){0.f, 0.f, 0.f, 0.f};

    auto stageA = [&](int s, int abuf) -> int {  // 128 rows x 32 u16; wave w: rows 16w..16w+15
        u16* dst = &lds[abuf * 4096 + w * 512];
        if (s < 24) {
            int seg = s >> 3, cs = s & 7;
            int tb = t0 + 16 * w + (seg - 1) * dil;
            if (tb >= 0 && tb + 16 <= T) {
                gl_lds16(xb + (size_t)(tb + lrow) * 256 + cs * 32 + lsw, dst);
                return 1;
            } else {  // boundary tile: manual masked path (rare)
                int t = tb + lrow;
                short8 av = (short8){0, 0, 0, 0, 0, 0, 0, 0};
                if (t >= 0 && t < T)
                    av = *(const short8*)(xb + (size_t)t * 256 + cs * 32 + lsw);
                *(short4v*)&dst[lane * 8] = __builtin_shufflevector(av, av, 0, 1, 2, 3);
                *(short4v*)&dst[lane * 8 + 4] = __builtin_shufflevector(av, av, 4, 5, 6, 7);
                return 0;
            }
        } else {
            gl_lds16(cb + (size_t)(t0 + 16 * w + lrow) * 96 + (s - 24) * 32 + lsw, dst);
            return 1;
        }
    };
    auto stageB = [&](int s, int bbuf) {  // 512 rows x 32 u16; wave w: 64 rows from brb
        const u16* src = Wl + (size_t)(brb + lrow) * 864 + s * 32 + lsw;
        u16* dst = &lds[12288 + bbuf * 16384 + w * 2048];
        gl_lds16(src, dst);
        gl_lds16(src + (size_t)16 * 864, dst + 512);
        gl_lds16(src + (size_t)32 * 864, dst + 1024);
        gl_lds16(src + (size_t)48 * 864, dst + 1536);
    };

    int a0 = stageA(0, 0);
    stageB(0, 0);
    int a1 = stageA(1, 1);
    stageB(1, 1);
    (void)a0;
    if (a1) wb5(); else wb4();
#pragma unroll 1
    for (int s = 0; s < 27; s++) {
        int aiss = 0;
        if (s + 2 < 27) {
            aiss = stageA(s + 2, (s + 2) % 3);
            stageB(s + 2, (s + 2) % 3);
        }
        const u16* bA = &lds[(s % 3) * 4096];
        const u16* bB = &lds[12288 + (s % 3) * 16384];
        short8 af0 = *(const short8*)&bA[(64 * iw + l15) * 32 + rq];
        short8 af1 = *(const short8*)&bA[(64 * iw + 16 + l15) * 32 + rq];
        short8 af2 = *(const short8*)&bA[(64 * iw + 32 + l15) * 32 + rq];
        short8 af3 = *(const short8*)&bA[(64 * iw + 48 + l15) * 32 + rq];
        __builtin_amdgcn_s_setprio(1);
#pragma unroll
        for (int jj = 0; jj < 8; jj++) {
            short8 bf = *(const short8*)&bB[(128 * jc + 16 * jj + l15) * 32 + rq];
            acc[0][jj] = __builtin_amdgcn_mfma_f32_16x16x32_bf16(af0, bf, acc[0][jj], 0, 0, 0);
            acc[1][jj] = __builtin_amdgcn_mfma_f32_16x16x32_bf16(af1, bf, acc[1][jj], 0, 0, 0);
            acc[2][jj] = __builtin_amdgcn_mfma_f32_16x16x32_bf16(af2, bf, acc[2][jj], 0, 0, 0);
            acc[3][jj] = __builtin_amdgcn_mfma_f32_16x16x32_bf16(af3, bf, acc[3][jj], 0, 0, 0);
        }
        __builtin_amdgcn_s_setprio(0);
        if (s < 25) {
            if (aiss) wb5(); else wb4();
        } else if (s == 25) {
            wb0();
        }
    }

    // gate in-wave: acc[m][jj] = tanh input, acc[m][jj+4] = sigm input, same col.
    u16* ab = acts + (size_t)b * T * 256;
#pragma unroll
    for (int m = 0; m < 4; m++)
#pragma unroll
        for (int jj = 0; jj < 4; jj++) {
            int o = 64 * jc + 16 * jj + l15;
#pragma unroll
            for (int r = 0; r < 4; r++) {
                int t = t0 + 64 * iw + 16 * m + quad * 4 + r;
                float at = acc[m][jj][r], as = acc[m][jj + 4][r];
                float e2 = __expf(2.f * at);
                float th = 1.f - 2.f / (e2 + 1.f);
                float sg = 1.f / (1.f + __expf(-as));
                ab[(size_t)t * 256 + o] = f2b(th * sg);
            }
        }
}

// ================= layer rs kernel (R10 + T1 swizzle): 1x1 conv (K=256) + residual/skip =====
// Same geometry + paired permutation (jj<4 residual rows, jj>=4 skip rows of same cols).
__global__ __launch_bounds__(512, 1) void layer_rs(
    const u16* __restrict__ acts, u16* __restrict__ x, const u16* __restrict__ Wrs,
    const u16* __restrict__ rsb, u16* __restrict__ oacc, int layer, int first, int last) {
    __shared__ u16 lds[61440];
    const int tid = threadIdx.x;
    const int w = tid >> 6, lane = tid & 63;
    const int l15 = lane & 15, quad = lane >> 4;
    const int iw = w >> 2, jc = w & 3;
    const int lin = blockIdx.x + 32 * blockIdx.y;                 // 0..255
    const int b = lin & 7, t0 = (lin >> 3) * 128;                 // T1 XCD swizzle
    const int lrow = lane >> 2;
    const int fw = (lrow ^ (lrow >> 2)) & 3;
    const int lsw = ((lane & 3) ^ fw) * 8;
    const int fr = (l15 ^ (l15 >> 2)) & 3;
    const int rq = (quad ^ fr) * 8;
    const int brb = 64 * (w >> 1) + 256 * (w & 1);

    const u16* ab = acts + (size_t)b * T * 256;
    const u16* Wr = Wrs + (size_t)layer * 512 * 256;

    float4v acc[4][8];
#pragma unroll
    for (int m = 0; m < 4; m++)
#pragma unroll
        for (int jj = 0; jj < 8; jj++) acc[m][jj] = (float4v){0.f, 0.f, 0.f, 0.f};

    auto stageA = [&](int s, int abuf) {
        gl_lds16(ab + (size_t)(t0 + 16 * w + lrow) * 256 + s * 32 + lsw,
                 &lds[abuf * 4096 + w * 512]);
    };
    auto stageB = [&](int s, int bbuf) {
        const u16* src = Wr + (size_t)(brb + lrow) * 256 + s * 32 + lsw;
        u16* dst = &lds[12288 + bbuf * 16384 + w * 2048];
        gl_lds16(src, dst);
        gl_lds16(src + (size_t)16 * 256, dst + 512);
        gl_lds16(src + (size_t)32 * 256, dst + 1024);
        gl_lds16(src + (size_t)48 * 256, dst + 1536);
    };

    stageA(0, 0);
    stageB(0, 0);
    stageA(1, 1);
    stageB(1, 1);
    wb5();
#pragma unroll 1
    for (int s = 0; s < 8; s++) {
        if (s + 2 < 8) {
            stageA(s + 2, (s + 2) % 3);
            stageB(s + 2, (s + 2) % 3);
        }
        const u16* bA = &lds[(s % 3) * 4096];
        const u16* bB = &lds[12288 + (s % 3) * 16384];
        short8 af0 = *(const short8*)&bA[(64 * iw + l15) * 32 + rq];
        short8 af1 = *(const short8*)&bA[(64 * iw + 16 + l15) * 32 + rq];
        short8 af2 = *(const short8*)&bA[(64 * iw + 32 + l15) * 32 + rq];
        short8 af3 = *(const short8*)&bA[(64 * iw + 48 + l15) * 32 + rq];
        __builtin_amdgcn_s_setprio(1);
#pragma unroll
        for (int jj = 0; jj < 8; jj++) {
            short8 bf = *(const short8*)&bB[(128 * jc + 16 * jj + l15) * 32 + rq];
            acc[0][jj] = __builtin_amdgcn_mfma_f32_16x16x32_bf16(af0, bf, acc[0][jj], 0, 0, 0);
            acc[1][jj] = __builtin_amdgcn_mfma_f32_16x16x32_bf16(af1, bf, acc[1][jj], 0, 0, 0);
            acc[2][jj] = __builtin_amdgcn_mfma_f32_16x16x32_bf16(af2, bf, acc[2][jj], 0, 0, 0);
            acc[3][jj] = __builtin_amdgcn_mfma_f32_16x16x32_bf16(af3, bf, acc[3][jj], 0, 0, 0);
        }
        __builtin_amdgcn_s_setprio(0);
        if (s < 6) wb5();
        else if (s == 6) wb0();
    }

    u16* xv = x + (size_t)b * T * 256;
    u16* oo = oacc + (size_t)b * T * 256;
#pragma unroll
    for (int m = 0; m < 4; m++)
#pragma unroll
        for (int jj = 0; jj < 8; jj++) {
            int o = 64 * jc + 16 * (jj & 3) + l15;
            if (jj < 4) {  // residual half (Wrs rows 0..255)
                float b0 = b2f(rsb[layer * 512 + o]);
#pragma unroll
                for (int r = 0; r < 4; r++) {
                    int t = t0 + 64 * iw + 16 * m + quad * 4 + r;
                    size_t idx = (size_t)t * 256 + o;
                    float v0 = acc[m][jj][r] + b0;
                    if (last) oo[idx] = f2b(b2f(oo[idx]) + v0);   // last: rs[:256] -> skip
                    else      xv[idx] = f2b(b2f(xv[idx]) + v0);   // residual (in place)
                }
            } else if (!last) {  // skip half (Wrs rows 256..511)
                float b1 = b2f(rsb[layer * 512 + 256 + o]);
#pragma unroll
                for (int r = 0; r < 4; r++) {
                    int t = t0 + 64 * iw + 16 * m + quad * 4 + r;
                    size_t idx = (size_t)t * 256 + o;
                    float v1 = acc[m][jj][r] + b1;
                    oo[idx] = first ? f2b(v1) : f2b(b2f(oo[idx]) + v1);
                }
            }
        }
}

// ---------------- end conv (256 -> 8) + affine + output assembly ----------------
template <bool F32>
__device__ __forceinline__ void end_body(const u16* __restrict__ oacc,
                                         const void* __restrict__ w_end,
                                         const void* __restrict__ b_end,
                                         const void* __restrict__ fc, void* __restrict__ out,
                                         float* wsm, float* bsm) {
    const int tid = threadIdx.x;
    for (int it = 0; it < 8; it++) wsm[it * 256 + tid] = LD<F32>(w_end, it * 256 + tid);
    if (tid < 8) bsm[tid] = LD<F32>(b_end, tid);
    __syncthreads();
    int gid = blockIdx.x * 256 + tid;  // 0..32767
    int b = gid >> 12, t = gid & 4095;
    float o8[8];
#pragma unroll
    for (int o = 0; o < 8; o++) o8[o] = bsm[o];
    const u16* orow = oacc + (size_t)(b * T + t) * 256;
    for (int c8 = 0; c8 < 32; c8++) {
        short8 v8 = *(const short8*)(orow + c8 * 8);
#pragma unroll
        for (int k = 0; k < 8; k++) {
            float v = b2f((u16)v8[k]);
            int c = c8 * 8 + k;
#pragma unroll
            for (int o = 0; o < 8; o++) o8[o] += wsm[o * 256 + c] * v;
        }
    }
    size_t ob8 = (size_t)b * 8 * T;
#pragma unroll
    for (int j = 0; j < 4; j++) {
        float f1v = LD<F32>(fc, ob8 + (size_t)(4 + j) * T + t);
        float ls = o8[4 + j];
        float val = __expf(ls) * f1v + o8[j];
        if constexpr (F32) {
            float* o = (float*)out;
            o[ob8 + (size_t)j * T + t] = ((const float*)fc)[ob8 + (size_t)j * T + t];
            o[ob8 + (size_t)(4 + j) * T + t] = val;
            o[(size_t)BATCH * 8 * T + ((size_t)b * 4 + j) * T + t] = ls;
        } else {
            u16* o = (u16*)out;
            o[ob8 + (size_t)j * T + t] = ((const u16*)fc)[ob8 + (size_t)j * T + t];
            o[ob8 + (size_t)(4 + j) * T + t] = f2b(val);
            o[(size_t)BATCH * 8 * T + ((size_t)b * 4 + j) * T + t] = f2b(ls);
        }
    }
}
__global__ void end_kernel(const u16* __restrict__ oacc, const void* __restrict__ w_end,
                           const void* __restrict__ b_end, const void* __restrict__ fc,
                           void* __restrict__ out, const int* __restrict__ flag) {
    __shared__ float wsm[2048];
    __shared__ float bsm[8];
    if (*flag) end_body<false>(oacc, w_end, b_end, fc, out, wsm, bsm);
    else       end_body<true>(oacc, w_end, b_end, fc, out, wsm, bsm);
}

extern "C" void kernel_launch(void* const* d_in, const int* in_sizes, int n_in,
                              void* d_out, int out_size, void* d_ws, size_t ws_size,
                              hipStream_t stream) {
    const void* forecast = d_in[0];
    const void* context  = d_in[1];
    const void* start_w  = d_in[2];
    const void* start_b  = d_in[3];
    const void* cond_w   = d_in[4];
    const void* cond_b   = d_in[5];
    const void* in_w     = d_in[6];
    const void* in_b     = d_in[7];
    const void* rs_w     = d_in[8];
    const void* rs_b     = d_in[9];
    const void* end_w    = d_in[10];
    const void* end_b    = d_in[11];

    char* W = (char*)d_ws;
    int* flag = (int*)(W + 0);
    u16* xA   = (u16*)(W + 256);                  // 16,777,216
    u16* oacc = (u16*)(W + 256 + 16777216);       // 16,777,216
    u16* acts = (u16*)(W + 256 + 33554432);       // 16,777,216
    u16* ctxt = (u16*)(W + 256 + 50331648);       //  6,291,456
    u16* Wc   = (u16*)(W + 256 + 56623104);       //  7,077,888
    u16* Wrs  = (u16*)(W + 256 + 63700992);       //  2,097,152
    u16* rsb  = (u16*)(W + 256 + 65798144);       //      8,192  -> total ~62.8 MiB

    probe_kernel<<<1, 256, 0, stream>>>((const u16*)forecast, flag);

    // single-pass prep (runtime dtype branch inside each kernel)
    cvt_kernel<<<4096, 256, 0, stream>>>(rs_w, Wrs, 8 * 512 * 256, flag);
    cvt_kernel<<<16, 256, 0, stream>>>(rs_b, rsb, 4096, flag);
    prep_wc<<<4096, 256, 0, stream>>>(in_w, in_b, cond_w, cond_b, Wc, flag);
    prep_ctx<<<dim3(64, BATCH), 256, 0, stream>>>(context, ctxt, flag);
    start_kernel<<<dim3(64, BATCH), 256, 0, stream>>>(forecast, start_w, start_b, xA, flag);

    const int dil[NLAYERS] = {1, 2, 4, 8, 16, 32, 64, 128};
    for (int l = 0; l < NLAYERS; l++) {
        layer_conv<<<dim3(32, BATCH), 512, 0, stream>>>(xA, Wc, ctxt, acts, l, dil[l]);
        layer_rs<<<dim3(32, BATCH), 512, 0, stream>>>(acts, xA, Wrs, rsb, oacc, l,
                                                      l == 0, l == NLAYERS - 1);
    }

    end_kernel<<<128, 256, 0, stream>>>(oacc, end_w, end_b, forecast, d_out, flag);
}